// Round 22
// baseline (251.973 us; speedup 1.0000x reference)
//
#include <hip/hip_runtime.h>
#include <hip/hip_bf16.h>

#define T_SEQ 4096
#define NB 4
#define CEMB 2048
#define HS 128

typedef __attribute__((ext_vector_type(8))) short bf16x8;
typedef __attribute__((ext_vector_type(4))) float f32x4;
typedef __attribute__((ext_vector_type(16))) float f32x16;

__device__ inline short f2bf(float f) {
    union { float f; unsigned u; } v; v.f = f;
    unsigned r = v.u + 0x7FFFu + ((v.u >> 16) & 1u);   // RNE
    return (short)(r >> 16);
}

__device__ inline unsigned pk2(float lo, float hi) {
    unsigned r;
    asm("v_cvt_pk_bf16_f32 %0, %1, %2" : "=v"(r) : "v"(lo), "v"(hi));
    return r;
}

__device__ inline void gld16(const void* gsrc, void* lds) {
    __builtin_amdgcn_global_load_lds(
        (const __attribute__((address_space(1))) unsigned*)gsrc,
        (__attribute__((address_space(3))) unsigned*)lds, 16, 0, 0);
}

// ---------------- kernel 1: W -> per-wave fragment-packed quarter panels -----
// Layout (shorts): mat*262144 + s2*4096 + wq*1024 + ct*512 + l*8 + j
// Element: col = wq*32 + ct*16 + (l&15), k = s2*32 + ((l>>4)<<3) + j.
__global__ __launch_bounds__(256) void wt_kernel(
    const float* __restrict__ Wq, const float* __restrict__ Wk,
    const float* __restrict__ Wv, short* __restrict__ Wt) {
    int d = blockIdx.x * 256 + threadIdx.x;     // 786432
    int j   = d & 7;
    int l   = (d >> 3) & 63;
    int ct  = (d >> 9) & 1;
    int wq  = (d >> 10) & 3;
    int s2  = (d >> 12) & 63;
    int mat = d >> 18;
    int col = wq * 32 + ct * 16 + (l & 15);
    int k   = s2 * 32 + ((l >> 4) << 3) + j;
    const float* W = (mat == 0) ? Wq : (mat == 1) ? Wk : Wv;
    Wt[d] = f2bf(W[k * HS + col]);
}

// ---------------- kernel 2: q/k/v projection v8c -- BARRIER-FREE -------------
// Wave-private staging; NO __syncthreads. vmcnt ledger (verified invariant):
// survivors at each wait = x(s+1):8 exactly, because sched_barrier(0) after
// STAGE pins W(s+1) issue BEFORE x(s+2) (v8b's NaN: scheduler hoisted the
// non-aliasing x loads above the gld16s, corrupting queue order).
// STEP(s): vmcnt(8) drains {x(s),W(s)}; STAGE(s+1); SBAR; ds_read+MFMA;
// LOADX(s+2).
__global__ __launch_bounds__(256, 3) void proj_kernel(
    const float* __restrict__ x, const short* __restrict__ Wt,
    short* __restrict__ qg, short* __restrict__ kg, short* __restrict__ vtg) {
    __shared__ short Wlds[2][4][1024];   // [buf][wave][2KB quarter] = 16KB

    const int tid = threadIdx.x;
    const int w   = tid >> 6;
    const int l   = tid & 63;
    const int lg  = l >> 4;
    const int lr  = l & 15;

    const int bid = blockIdx.x;
    const int wk  = (bid & 7) * 96 + (bid >> 3);   // same-XCD chunking
    const int mat = wk % 3;
    const int m0  = (wk / 3) * 64;

    const short* Wp = Wt + (long)mat * 262144 + w * 1024;

    f32x4 acc[4][2];   // [row group][col tile]
    #pragma unroll
    for (int a = 0; a < 4; a++)
        #pragma unroll
        for (int b = 0; b < 2; b++) acc[a][b] = (f32x4){0.f, 0.f, 0.f, 0.f};

    const float* xr0 = x + (long)(m0 + 0 * 16 + lr) * CEMB + lg * 8;
    const float* xr1 = x + (long)(m0 + 1 * 16 + lr) * CEMB + lg * 8;
    const float* xr2 = x + (long)(m0 + 2 * 16 + lr) * CEMB + lg * 8;
    const float* xr3 = x + (long)(m0 + 3 * 16 + lr) * CEMB + lg * 8;

    float4 xs[2][8];   // [slot][rgp*2 + half], all indices compile-time

#define STAGE(S2, B) do {                                                  \
        const short* gp_ = Wp + (long)(S2) * 4096 + l * 8;                 \
        gld16(gp_,       &Wlds[B][w][0]);                                  \
        gld16(gp_ + 512, &Wlds[B][w][512]);                                \
    } while (0)

#define LOADX(S2, XB) do {                                                 \
        xs[XB][0] = *reinterpret_cast<const float4*>(xr0 + (S2) * 32);     \
        xs[XB][1] = *reinterpret_cast<const float4*>(xr0 + (S2) * 32 + 4); \
        xs[XB][2] = *reinterpret_cast<const float4*>(xr1 + (S2) * 32);     \
        xs[XB][3] = *reinterpret_cast<const float4*>(xr1 + (S2) * 32 + 4); \
        xs[XB][4] = *reinterpret_cast<const float4*>(xr2 + (S2) * 32);     \
        xs[XB][5] = *reinterpret_cast<const float4*>(xr2 + (S2) * 32 + 4); \
        xs[XB][6] = *reinterpret_cast<const float4*>(xr3 + (S2) * 32);     \
        xs[XB][7] = *reinterpret_cast<const float4*>(xr3 + (S2) * 32 + 4); \
    } while (0)

#define STEP(S2) do {                                                      \
        asm volatile("s_waitcnt vmcnt(8)" ::: "memory");                   \
        if ((S2) + 1 < 64) {                                               \
            STAGE((S2) + 1, ((S2) + 1) & 1);                               \
            __builtin_amdgcn_sched_barrier(0);   /* pin W before x */      \
        }                                                                  \
        const char* lb_ = (const char*)&Wlds[(S2) & 1][w][0] + l * 16;     \
        bf16x8 b0_ = *reinterpret_cast<const bf16x8*>(lb_);                \
        bf16x8 b1_ = *reinterpret_cast<const bf16x8*>(lb_ + 1024);        \
        bf16x8 A0_, A1_, A2_, A3_;                                         \
        {                                                                  \
            union { unsigned u[4]; bf16x8 v; } U_;                         \
            U_.u[0] = pk2(xs[(S2) & 1][0].x, xs[(S2) & 1][0].y);           \
            U_.u[1] = pk2(xs[(S2) & 1][0].z, xs[(S2) & 1][0].w);           \
            U_.u[2] = pk2(xs[(S2) & 1][1].x, xs[(S2) & 1][1].y);           \
            U_.u[3] = pk2(xs[(S2) & 1][1].z, xs[(S2) & 1][1].w);           \
            A0_ = U_.v;                                                    \
            U_.u[0] = pk2(xs[(S2) & 1][2].x, xs[(S2) & 1][2].y);           \
            U_.u[1] = pk2(xs[(S2) & 1][2].z, xs[(S2) & 1][2].w);           \
            U_.u[2] = pk2(xs[(S2) & 1][3].x, xs[(S2) & 1][3].y);           \
            U_.u[3] = pk2(xs[(S2) & 1][3].z, xs[(S2) & 1][3].w);           \
            A1_ = U_.v;                                                    \
            U_.u[0] = pk2(xs[(S2) & 1][4].x, xs[(S2) & 1][4].y);           \
            U_.u[1] = pk2(xs[(S2) & 1][4].z, xs[(S2) & 1][4].w);           \
            U_.u[2] = pk2(xs[(S2) & 1][5].x, xs[(S2) & 1][5].y);           \
            U_.u[3] = pk2(xs[(S2) & 1][5].z, xs[(S2) & 1][5].w);           \
            A2_ = U_.v;                                                    \
            U_.u[0] = pk2(xs[(S2) & 1][6].x, xs[(S2) & 1][6].y);           \
            U_.u[1] = pk2(xs[(S2) & 1][6].z, xs[(S2) & 1][6].w);           \
            U_.u[2] = pk2(xs[(S2) & 1][7].x, xs[(S2) & 1][7].y);           \
            U_.u[3] = pk2(xs[(S2) & 1][7].z, xs[(S2) & 1][7].w);           \
            A3_ = U_.v;                                                    \
        }                                                                  \
        if ((S2) + 2 < 64) LOADX((S2) + 2, (S2) & 1);                      \
        acc[0][0] = __builtin_amdgcn_mfma_f32_16x16x32_bf16(A0_, b0_, acc[0][0], 0, 0, 0); \
        acc[0][1] = __builtin_amdgcn_mfma_f32_16x16x32_bf16(A0_, b1_, acc[0][1], 0, 0, 0); \
        acc[1][0] = __builtin_amdgcn_mfma_f32_16x16x32_bf16(A1_, b0_, acc[1][0], 0, 0, 0); \
        acc[1][1] = __builtin_amdgcn_mfma_f32_16x16x32_bf16(A1_, b1_, acc[1][1], 0, 0, 0); \
        acc[2][0] = __builtin_amdgcn_mfma_f32_16x16x32_bf16(A2_, b0_, acc[2][0], 0, 0, 0); \
        acc[2][1] = __builtin_amdgcn_mfma_f32_16x16x32_bf16(A2_, b1_, acc[2][1], 0, 0, 0); \
        acc[3][0] = __builtin_amdgcn_mfma_f32_16x16x32_bf16(A3_, b0_, acc[3][0], 0, 0, 0); \
        acc[3][1] = __builtin_amdgcn_mfma_f32_16x16x32_bf16(A3_, b1_, acc[3][1], 0, 0, 0); \
    } while (0)

    // prologue: W0 (oldest, pinned), x0, x1 -> queue 18
    STAGE(0, 0);
    __builtin_amdgcn_sched_barrier(0);
    LOADX(0, 0);
    LOADX(1, 1);

    #pragma unroll
    for (int s2 = 0; s2 < 63; ++s2) STEP(s2);
    // final substep: drain everything
    {
        asm volatile("s_waitcnt vmcnt(0)" ::: "memory");
        const char* lb_ = (const char*)&Wlds[63 & 1][w][0] + l * 16;
        bf16x8 b0_ = *reinterpret_cast<const bf16x8*>(lb_);
        bf16x8 b1_ = *reinterpret_cast<const bf16x8*>(lb_ + 1024);
        union { unsigned u[4]; bf16x8 v; } U_;
        bf16x8 A_[4];
        #pragma unroll
        for (int rgp = 0; rgp < 4; rgp++) {
            U_.u[0] = pk2(xs[1][rgp * 2].x, xs[1][rgp * 2].y);
            U_.u[1] = pk2(xs[1][rgp * 2].z, xs[1][rgp * 2].w);
            U_.u[2] = pk2(xs[1][rgp * 2 + 1].x, xs[1][rgp * 2 + 1].y);
            U_.u[3] = pk2(xs[1][rgp * 2 + 1].z, xs[1][rgp * 2 + 1].w);
            A_[rgp] = U_.v;
        }
        #pragma unroll
        for (int rgp = 0; rgp < 4; rgp++) {
            acc[rgp][0] = __builtin_amdgcn_mfma_f32_16x16x32_bf16(A_[rgp], b0_, acc[rgp][0], 0, 0, 0);
            acc[rgp][1] = __builtin_amdgcn_mfma_f32_16x16x32_bf16(A_[rgp], b1_, acc[rgp][1], 0, 0, 0);
        }
    }

#undef STEP
#undef LOADX
#undef STAGE

    // ---- store: rows m0 + rgp*16 + lg*4 + r, cols w*32 + ct*16 + lr ----
    if (mat == 0) {
        const float scale = 0.0318793851f;  // log2(e)/sqrt(2048) folded into q
        #pragma unroll
        for (int rgp = 0; rgp < 4; rgp++)
            #pragma unroll
            for (int ct = 0; ct < 2; ct++)
                #pragma unroll
                for (int r = 0; r < 4; r++) {
                    int row = m0 + rgp * 16 + lg * 4 + r;
                    int col = w * 32 + ct * 16 + lr;
                    qg[(long)row * HS + col] = f2bf(acc[rgp][ct][r] * scale);
                }
    } else if (mat == 1) {
        // K image: 8192 shorts/tile; byte = (r64*256 + d*2) ^ ((r64&7)<<4)
        short* kt = kg + ((long)(m0 >> 6)) * 8192;
        #pragma unroll
        for (int rgp = 0; rgp < 4; rgp++)
            #pragma unroll
            for (int ct = 0; ct < 2; ct++)
                #pragma unroll
                for (int r = 0; r < 4; r++) {
                    int r64  = rgp * 16 + lg * 4 + r;
                    int d0   = w * 32 + ct * 16 + lr;
                    int byte = (r64 * 256 + d0 * 2) ^ ((r64 & 7) << 4);
                    kt[byte >> 1] = f2bf(acc[rgp][ct][r]);
                }
    } else {
        #pragma unroll
        for (int rgp = 0; rgp < 4; rgp++)
            #pragma unroll
            for (int ct = 0; ct < 2; ct++)
                #pragma unroll
                for (int r = 0; r < 4; r++) {
                    int row = m0 + rgp * 16 + lg * 4 + r;
                    int b2  = row >> 12;
                    int tl  = row & 4095;
                    int d0  = w * 32 + ct * 16 + lr;
                    vtg[(long)b2 * (HS * T_SEQ) + (long)d0 * T_SEQ + tl]
                        = f2bf(acc[rgp][ct][r]);
                }
    }
}

// ---------------- kernel 3: flash attention v5 (unchanged, known-good) -------
__global__ __launch_bounds__(512, 2) void attn_kernel(
    const short* __restrict__ qg, const short* __restrict__ kg,
    const short* __restrict__ vtg, float* __restrict__ out) {
    __shared__ __align__(16) char pool[131072];   // 8 waves x 16KB
    __shared__ float Lm[8][32];
    __shared__ float Ll[8][32];

    const int tid = threadIdx.x;
    const int w   = tid >> 6;      // wave 0..7 = kv-split index
    const int l   = tid & 63;
    const int c31 = l & 31;
    const int hi  = l >> 5;
    const int hi4 = hi << 2;
    const int hi8 = hi << 3;

    const int bid = blockIdx.x;
    const int xcd = bid & 7;
    const int idx = bid >> 3;                        // 0..31
    const int b   = xcd >> 1;                        // batch pinned to XCD pair
    const int qtA = 127 - ((idx << 1) | (xcd & 1));  // 64..127

    const short* kbimg = kg + (long)b * 64 * 8192;   // 64 K-tile images per batch
    const short* vb    = vtg + (long)b * HS * T_SEQ;

    short* Kw = (short*)(pool + (w << 14));          // wave-private 16KB

#define STAGEK(TILE) do {                                                  \
        const short* gp_ = kbimg + (long)(TILE) * 8192 + l * 8;            \
        _Pragma("unroll")                                                  \
        for (int i = 0; i < 16; i++)                                       \
            gld16(gp_ + i * 512, Kw + i * 512 + l * 8);                    \
    } while (0)

    const int swz = (c31 & 7) << 4;
    const int rbA = c31 * 256;
    const int rbB = (32 + c31) * 256;

    #pragma unroll 1
    for (int ph = 0; ph < 2; ++ph) {
        const int qt   = ph ? (127 - qtA) : qtA;
        const int q0   = qt * 32;
        const int qrow = q0 + c31;
        const int ntk  = (qt >> 1) + 1;

        bf16x8 qf[8];
        #pragma unroll
        for (int kc = 0; kc < 8; kc++)
            qf[kc] = *reinterpret_cast<const bf16x8*>(
                &qg[(long)(b * T_SEQ + qrow) * HS + kc * 16 + hi8]);

        f32x16 accO[4];
        #pragma unroll
        for (int nb = 0; nb < 4; nb++)
            #pragma unroll
            for (int i = 0; i < 16; i++) accO[nb][i] = 0.f;
        float mrow = -__builtin_inff();
        float lsum = 0.f;

        if (w < ntk) STAGEK(w);

        #pragma unroll 1
        for (int t = w; t < ntk; t += 8) {
            const int kv0 = t * 64;

            asm volatile("s_waitcnt vmcnt(0)" ::: "memory");

            bf16x8 vfA[2][4];
            #pragma unroll
            for (int kc = 0; kc < 2; kc++)
                #pragma unroll
                for (int nb = 0; nb < 4; nb++)
                    vfA[kc][nb] = *reinterpret_cast<const bf16x8*>(
                        &vb[(long)(nb * 32 + c31) * T_SEQ + kv0 + kc * 16 + hi8]);

            f32x16 SA, SB;
            #pragma unroll
            for (int i = 0; i < 16; i++) { SA[i] = 0.f; SB[i] = 0.f; }
            __builtin_amdgcn_s_setprio(1);
            #pragma unroll
            for (int kc = 0; kc < 8; kc++) {
                const int cb = kc * 32 + hi * 16;
                bf16x8 ka = *reinterpret_cast<const bf16x8*>(
                    (const char*)Kw + ((rbA + cb) ^ swz));
                bf16x8 kb2 = *reinterpret_cast<const bf16x8*>(
                    (const char*)Kw + ((rbB + cb) ^ swz));
                SA = __builtin_amdgcn_mfma_f32_32x32x16_bf16(ka,  qf[kc], SA, 0, 0, 0);
                SB = __builtin_amdgcn_mfma_f32_32x32x16_bf16(kb2, qf[kc], SB, 0, 0, 0);
            }
            __builtin_amdgcn_s_setprio(0);

            if (t + 8 < ntk) STAGEK(t + 8);

            float pA[16], pB[16];
            #pragma unroll
            for (int r = 0; r < 16; r++) { pA[r] = SA[r]; pB[r] = SB[r]; }

            if (kv0 + 63 > q0) {
                #pragma unroll
                for (int r = 0; r < 16; r++) {
                    int kr = kv0 + (r & 3) + 8 * (r >> 2) + hi4;
                    pA[r] = (kr > qrow)      ? -__builtin_inff() : pA[r];
                    pB[r] = (kr + 32 > qrow) ? -__builtin_inff() : pB[r];
                }
            }

            float t16[16];
            #pragma unroll
            for (int r = 0; r < 16; r++) t16[r] = fmaxf(pA[r], pB[r]);
            #pragma unroll
            for (int s2 = 8; s2 >= 1; s2 >>= 1)
                #pragma unroll
                for (int r = 0; r < 8; r++)
                    if (r < s2) t16[r] = fmaxf(t16[r], t16[r + s2]);
            float mt = fmaxf(t16[0], __shfl_xor(t16[0], 32));

            if (__any(mt > mrow)) {
                float mnew = fmaxf(mrow, mt);
                float fac  = exp2f(mrow - mnew);
                lsum *= fac;
                #pragma unroll
                for (int nb = 0; nb < 4; nb++)
                    #pragma unroll
                    for (int i = 0; i < 16; i++) accO[nb][i] *= fac;
                mrow = mnew;
            }

            bf16x8 vfB[2][4];
            #pragma unroll
            for (int kc = 0; kc < 2; kc++)
                #pragma unroll
                for (int nb = 0; nb < 4; nb++)
                    vfB[kc][nb] = *reinterpret_cast<const bf16x8*>(
                        &vb[(long)(nb * 32 + c31) * T_SEQ + kv0 + (kc + 2) * 16 + hi8]);

            #pragma unroll
            for (int r = 0; r < 16; r++) {
                pA[r] = exp2f(pA[r] - mrow);
                pB[r] = exp2f(pB[r] - mrow);
            }
            float s16[16];
            #pragma unroll
            for (int r = 0; r < 16; r++) s16[r] = pA[r] + pB[r];
            #pragma unroll
            for (int s2 = 8; s2 >= 1; s2 >>= 1)
                #pragma unroll
                for (int r = 0; r < 8; r++)
                    if (r < s2) s16[r] += s16[r + s2];
            lsum += s16[0] + __shfl_xor(s16[0], 32);

            bf16x8 pf[4];
            #pragma unroll
            for (int kc = 0; kc < 4; kc++) {
                const int V0 = 2 * kc, V1 = 2 * kc + 1;
                const int r0 = ((V0 >> 2) << 4) | ((V0 & 3) << 2);
                const int r1 = ((V1 >> 2) << 4) | ((V1 & 3) << 2);
#define PSEL(i) ((i) < 16 ? pA[(i) & 15] : pB[(i) & 15])
                unsigned a0 = pk2(PSEL(r0 + 0), PSEL(r0 + 1));
                unsigned a1 = pk2(PSEL(r0 + 2), PSEL(r0 + 3));
                unsigned b0 = pk2(PSEL(r1 + 0), PSEL(r1 + 1));
                unsigned b1 = pk2(PSEL(r1 + 2), PSEL(r1 + 3));
#undef PSEL
                unsigned k0 = hi ? b0 : a0, k1 = hi ? b1 : a1;
                unsigned s0 = hi ? a0 : b0, s1 = hi ? a1 : b1;
                unsigned g0 = (unsigned)__shfl_xor((int)s0, 32);
                unsigned g1 = (unsigned)__shfl_xor((int)s1, 32);
                union { unsigned u[4]; bf16x8 v; } U;
                U.u[0] = hi ? g0 : k0;
                U.u[1] = hi ? g1 : k1;
                U.u[2] = hi ? k0 : g0;
                U.u[3] = hi ? k1 : g1;
                pf[kc] = U.v;
            }

            __builtin_amdgcn_s_setprio(1);
            #pragma unroll
            for (int nb = 0; nb < 4; nb++)
                accO[nb] = __builtin_amdgcn_mfma_f32_32x32x16_bf16(pf[0], vfA[0][nb], accO[nb], 0, 0, 0);
            #pragma unroll
            for (int nb = 0; nb < 4; nb++)
                accO[nb] = __builtin_amdgcn_mfma_f32_32x32x16_bf16(pf[1], vfA[1][nb], accO[nb], 0, 0, 0);
            #pragma unroll
            for (int nb = 0; nb < 4; nb++)
                accO[nb] = __builtin_amdgcn_mfma_f32_32x32x16_bf16(pf[2], vfB[0][nb], accO[nb], 0, 0, 0);
            #pragma unroll
            for (int nb = 0; nb < 4; nb++)
                accO[nb] = __builtin_amdgcn_mfma_f32_32x32x16_bf16(pf[3], vfB[1][nb], accO[nb], 0, 0, 0);
            __builtin_amdgcn_s_setprio(0);
        }

        __syncthreads();   // all waves done reading their K slices this phase
        {
            float* LaccW = (float*)(pool + (w << 14));   // [32][128]
            #pragma unroll
            for (int nb = 0; nb < 4; nb++)
                #pragma unroll
                for (int r = 0; r < 16; r++)
                    LaccW[((r & 3) + 8 * (r >> 2) + hi4) * 128 + nb * 32 + c31] = accO[nb][r];
            if (l < 32) { Lm[w][c31] = mrow; Ll[w][c31] = lsum; }
        }
        __syncthreads();

        {
            const int row = tid >> 4;
            const int c0  = (tid & 15) * 8;
            float mv[8], lv[8];
            #pragma unroll
            for (int p2 = 0; p2 < 8; p2++) { mv[p2] = Lm[p2][row]; lv[p2] = Ll[p2][row]; }
            float ms = mv[0];
            #pragma unroll
            for (int p2 = 1; p2 < 8; p2++) ms = fmaxf(ms, mv[p2]);
            float fv[8];
            float L = 0.f;
            #pragma unroll
            for (int p2 = 0; p2 < 8; p2++) { fv[p2] = exp2f(mv[p2] - ms); L += lv[p2] * fv[p2]; }
            float inv = 1.0f / L;
            float* op = &out[((long)b * T_SEQ + q0 + row) * HS + c0];
            #pragma unroll
            for (int j = 0; j < 8; j++) {
                float o = 0.f;
                #pragma unroll
                for (int p2 = 0; p2 < 8; p2++)
                    o += ((const float*)(pool + (p2 << 14)))[row * 128 + c0 + j] * fv[p2];
                op[j] = o * inv;
            }
        }
        __syncthreads();   // merge reads done before next phase restages K
    }
#undef STAGEK
}

// ---------------- launch ------------------------------------------------------
extern "C" void kernel_launch(void* const* d_in, const int* in_sizes, int n_in,
                              void* d_out, int out_size, void* d_ws, size_t ws_size,
                              hipStream_t stream) {
    const float* x  = (const float*)d_in[0];
    const float* Wk = (const float*)d_in[1];
    const float* Wq = (const float*)d_in[2];
    const float* Wv = (const float*)d_in[3];
    float* out = (float*)d_out;

    char* ws = (char*)d_ws;
    short* Wt  = (short*)ws;                                  // 1.5 MB (quarter-packed)
    short* qg  = (short*)(ws + 1572864);                      // 4 MB
    short* kg  = (short*)(ws + 1572864 + 4194304);            // 4 MB (K tile images)
    short* vtg = (short*)(ws + 1572864 + 8388608);            // 4 MB

    wt_kernel  <<<3072, 256, 0, stream>>>(Wq, Wk, Wv, Wt);
    proj_kernel<<<768,  256, 0, stream>>>(x, Wt, qg, kg, vtg);
    attn_kernel<<<256,  512, 0, stream>>>(qg, kg, vtg, out);
}